// Round 2
// baseline (529.391 us; speedup 1.0000x reference)
//
#include <hip/hip_runtime.h>
#include <hip/hip_bf16.h>
#include <math.h>

// Sizes (fixed): BATCH=2, SEQ=2048, DIM=768, HEADS=8, DK=DV=64, F=192, d_inner=512
// All internal compute in fp16 storage + fp32 MFMA accumulation.

typedef _Float16 f16x8 __attribute__((ext_vector_type(8)));
typedef _Float16 f16x4 __attribute__((ext_vector_type(4)));
typedef float f32x4 __attribute__((ext_vector_type(4)));

#define MFMA16(a, b, c) __builtin_amdgcn_mfma_f32_16x16x32_f16((a), (b), (c), 0, 0, 0)

// ---------------- f32 -> fp16 elementwise (vectorized x4) ----------------
__global__ __launch_bounds__(256) void cvt4_kernel(const float* __restrict__ in,
                                                   _Float16* __restrict__ out, int n4) {
  int idx = blockIdx.x * 256 + threadIdx.x;
  if (idx < n4) {
    float4 v = ((const float4*)in)[idx];
    f16x4 o;
    o[0] = (_Float16)v.x; o[1] = (_Float16)v.y; o[2] = (_Float16)v.z; o[3] = (_Float16)v.w;
    ((f16x4*)out)[idx] = o;
  }
}

// ---------------- f32 [K][N] -> fp16 transposed [N][K] ----------------
__global__ __launch_bounds__(256) void cvt_t_kernel(const float* __restrict__ in,
                                                    _Float16* __restrict__ out, int K, int N) {
  int idx = blockIdx.x * 256 + threadIdx.x;
  if (idx < K * N) {
    int k = idx / N, c = idx % N;
    out[(size_t)c * K + k] = (_Float16)in[idx];
  }
}

// ---------------- positional embedding: posb [4096][192] fp16 ----------------
// row r: distance = r - 2047. cols 0..31 exp basis, 32..63 center mask,
// 64..95 gamma pdf (row-max normalized), 96..191 = sign * cols 0..95.
// row 4095 = zeros (pad so rel_k band reads stay in-bounds).
__global__ __launch_bounds__(128) void pos_embed_kernel(_Float16* __restrict__ posb) {
  __shared__ float sg[32];
  const int r = blockIdx.x, t = threadIdx.x;
  if (r >= 4095) {
    if (t < 96) {
      posb[(size_t)r * 192 + t] = (_Float16)0.f;
      posb[(size_t)r * 192 + 96 + t] = (_Float16)0.f;
    }
    return;
  }
  const float dist = (float)(r - 2047);
  const float absd = fabsf(dist);
  const float sgn = (dist > 0.f) ? 1.f : ((dist < 0.f) ? -1.f : 0.f);
  float val = 0.f;
  if (t < 32) {
    // exp basis: 2^(-absd / half_life), half_life = 2^linspace(3, 11, 32)
    float e = 3.f + (float)t * (8.f / 31.f);
    float hl = exp2f(e);
    val = exp2f(-absd / hl);
  } else if (t < 64) {
    int i = t - 32;
    float cw = exp2f((float)(i + 1)) - 1.f;   // 2^(i+1) - 1
    val = (cw > absd) ? 1.f : 0.f;
  } else if (t < 96) {
    int i = t - 64;
    float mean = 64.f * (float)(i + 1);       // linspace(64, 2048, 32)
    float sd = 32.f;                           // 2048 / 64
    float conc = (mean / sd) * (mean / sd);
    float rate = mean / (sd * sd);
    float lu = (conc - 1.f) * logf(absd) - rate * absd;  // logf(0) = -inf: ok, conc>1
    float ln_ = lgammaf(conc) - conc * logf(rate);
    val = expf(lu - ln_) + 1e-8f;
    sg[i] = val;
  }
  __syncthreads();
  if (t >= 64 && t < 96) {
    float mx = sg[0];
#pragma unroll
    for (int i = 1; i < 32; ++i) mx = fmaxf(mx, sg[i]);
    val = val / mx;
  }
  if (t < 96) {
    posb[(size_t)r * 192 + t] = (_Float16)val;
    posb[(size_t)r * 192 + 96 + t] = (_Float16)(sgn * val);
  }
}

// ---------------- generic MFMA GEMM: C[M][*] = A[M][K] * Bt[N][K]^T ----------------
// 256 threads = 4 waves; block tile 64 rows x 64 cols; wave w -> rows [w*16, w*16+16).
// MODE 0: q-proj -> qc = acc*0.125 + bc[col], qp = acc*0.125 + bp[col], fp16 [b][h][n][64]
// MODE 1: k-proj -> fp16 [b][h][n][64]
// MODE 2: v-proj -> fp16 transposed [b][h][64][n]
// MODE 3: relk   -> fp16 [h][4096][64]  (row index = position index)
// MODE 4: out-proj -> f32 [row][N] + bias0[col]
template <int MODE>
__global__ __launch_bounds__(256) void gemm_bt(
    const _Float16* __restrict__ A, const _Float16* __restrict__ Bt, int N, int K,
    _Float16* __restrict__ out0, _Float16* __restrict__ out1,
    const float* __restrict__ bias0, const float* __restrict__ bias1,
    float* __restrict__ outf) {
  const int tid = threadIdx.x;
  const int w = tid >> 6, lane = tid & 63, g = lane >> 4, m = lane & 15;
  const int row0 = blockIdx.y * 64 + w * 16;
  const int c0 = blockIdx.x * 64;
  f32x4 acc[4] = {};
  const _Float16* Ap = A + (size_t)(row0 + m) * K + g * 8;
  const _Float16* Bp = Bt + (size_t)(c0 + m) * K + g * 8;
  for (int k0 = 0; k0 < K; k0 += 32) {
    f16x8 a = *(const f16x8*)(Ap + k0);
#pragma unroll
    for (int cf = 0; cf < 4; ++cf) {
      f16x8 bfr = *(const f16x8*)(Bp + (size_t)cf * 16 * K + k0);
      acc[cf] = MFMA16(a, bfr, acc[cf]);
    }
  }
#pragma unroll
  for (int cf = 0; cf < 4; ++cf) {
    const int col = c0 + cf * 16 + m;
    const int hh = col >> 6, dk = col & 63;
    float b0 = 0.f, b1 = 0.f;
    if (MODE == 0) { b0 = bias0[col]; b1 = bias1[col]; }
#pragma unroll
    for (int r = 0; r < 4; ++r) {
      const int row = row0 + g * 4 + r;
      const float v = acc[cf][r];
      if (MODE == 0) {
        const int bb = row >> 11, n = row & 2047;
        const size_t ad = ((size_t)(bb * 8 + hh) * 2048 + n) * 64 + dk;
        const float vs = v * 0.125f;  // DIM_KEY^-0.5
        out0[ad] = (_Float16)(vs + b0);
        out1[ad] = (_Float16)(vs + b1);
      } else if (MODE == 1) {
        const int bb = row >> 11, n = row & 2047;
        out0[((size_t)(bb * 8 + hh) * 2048 + n) * 64 + dk] = (_Float16)v;
      } else if (MODE == 2) {
        const int bb = row >> 11, n = row & 2047;
        out0[((size_t)(bb * 8 + hh) * 64 + dk) * 2048 + n] = (_Float16)v;
      } else if (MODE == 3) {
        out0[((size_t)hh * 4096 + row) * 64 + dk] = (_Float16)v;
      } else {
        outf[(size_t)row * N + col] = v + bias0[col];
      }
    }
  }
}

// ---------------- fused rel-pos attention ----------------
// grid (32 i-tiles, 16 b*h), 256 threads = 4 waves, wave w owns q rows [i0+w*16, +16).
// Per 64-wide j tile:
//   S_c = qc . K^T (MFMA), R = qp . relk[d0..d0+128)^T (MFMA, 128-wide band)
//   S = S_c + R[row, 63 + jj - ii]  (shift gather via LDS)
//   online softmax (m,l per row), P -> fp16 -> LDS -> A-fragments, acc += P.V (MFMA)
__global__ __launch_bounds__(256) void attn_kernel(
    const _Float16* __restrict__ qc, const _Float16* __restrict__ qp,
    const _Float16* __restrict__ kb, const _Float16* __restrict__ vtb,
    const _Float16* __restrict__ relkb, _Float16* __restrict__ attnb) {
  __shared__ float R_lds[4][16][128];
  __shared__ __align__(16) _Float16 P_lds[4][16][80];  // pad 64->80 for bank spread
  const int tid = threadIdx.x;
  const int w = tid >> 6, lane = tid & 63, g = lane >> 4, m = lane & 15;
  const int i0 = blockIdx.x * 64;
  const int bh = blockIdx.y;
  const int h = bh & 7, b = bh >> 3;
  const int row_w = i0 + w * 16;

  const size_t qbase = ((size_t)bh * 2048 + row_w + m) * 64 + g * 8;
  f16x8 qcf0 = *(const f16x8*)(qc + qbase);
  f16x8 qcf1 = *(const f16x8*)(qc + qbase + 32);
  f16x8 qpf0 = *(const f16x8*)(qp + qbase);
  f16x8 qpf1 = *(const f16x8*)(qp + qbase + 32);

  f32x4 acc_o[4] = {};
  float m_run[4], l_run[4];
#pragma unroll
  for (int r = 0; r < 4; ++r) { m_run[r] = -1e30f; l_run[r] = 0.f; }

  for (int jt = 0; jt < 32; ++jt) {
    const int j0 = jt * 64;
    // ---- content logits S_c [16 x 64] per wave ----
    f32x4 sc[4] = {};
    const size_t kbase = ((size_t)bh * 2048 + j0 + m) * 64 + g * 8;
#pragma unroll
    for (int cf = 0; cf < 4; ++cf) {
      f16x8 b0 = *(const f16x8*)(kb + kbase + (size_t)cf * 1024);
      f16x8 b1 = *(const f16x8*)(kb + kbase + (size_t)cf * 1024 + 32);
      sc[cf] = MFMA16(qcf0, b0, sc[cf]);
      sc[cf] = MFMA16(qcf1, b1, sc[cf]);
    }
    // ---- rel logits band R [16 x 128] per wave ----
    const int d0 = j0 - i0 + 1984;  // = j0 - i0 + (n-1) - 63 ; always in [0, 3968]
    const size_t rbase = ((size_t)h * 4096 + d0 + m) * 64 + g * 8;
    f32x4 rc[8] = {};
#pragma unroll
    for (int cf = 0; cf < 8; ++cf) {
      f16x8 b0 = *(const f16x8*)(relkb + rbase + (size_t)cf * 1024);
      f16x8 b1 = *(const f16x8*)(relkb + rbase + (size_t)cf * 1024 + 32);
      rc[cf] = MFMA16(qpf0, b0, rc[cf]);
      rc[cf] = MFMA16(qpf1, b1, rc[cf]);
    }
#pragma unroll
    for (int cf = 0; cf < 8; ++cf)
#pragma unroll
      for (int r = 0; r < 4; ++r)
        R_lds[w][g * 4 + r][cf * 16 + m] = rc[cf][r];
    __syncthreads();
    // ---- gather shifted rel + add ----
    float S[4][4];
#pragma unroll
    for (int cf = 0; cf < 4; ++cf)
#pragma unroll
      for (int r = 0; r < 4; ++r) {
        const int t = 63 + cf * 16 + m - w * 16 - g * 4 - r;  // in [0,126]
        S[cf][r] = sc[cf][r] + R_lds[w][g * 4 + r][t];
      }
    // ---- online softmax (rows owned per lane: r=0..3) ----
    float P[4][4];
#pragma unroll
    for (int r = 0; r < 4; ++r) {
      float mx = fmaxf(fmaxf(S[0][r], S[1][r]), fmaxf(S[2][r], S[3][r]));
      mx = fmaxf(mx, __shfl_xor(mx, 1));
      mx = fmaxf(mx, __shfl_xor(mx, 2));
      mx = fmaxf(mx, __shfl_xor(mx, 4));
      mx = fmaxf(mx, __shfl_xor(mx, 8));
      const float mnew = fmaxf(m_run[r], mx);
      const float corr = __expf(m_run[r] - mnew);
      float rs = 0.f;
#pragma unroll
      for (int cf = 0; cf < 4; ++cf) {
        float p = __expf(S[cf][r] - mnew);
        P[cf][r] = p;
        rs += p;
      }
      rs += __shfl_xor(rs, 1);
      rs += __shfl_xor(rs, 2);
      rs += __shfl_xor(rs, 4);
      rs += __shfl_xor(rs, 8);
      l_run[r] = l_run[r] * corr + rs;
      m_run[r] = mnew;
#pragma unroll
      for (int cf = 0; cf < 4; ++cf) acc_o[cf][r] *= corr;
    }
    // ---- P -> fp16 -> LDS (C-layout write, A-layout read) ----
#pragma unroll
    for (int cf = 0; cf < 4; ++cf)
#pragma unroll
      for (int r = 0; r < 4; ++r)
        P_lds[w][g * 4 + r][cf * 16 + m] = (_Float16)P[cf][r];
    __syncthreads();
    // ---- PV: acc_o += P . V  (V^T layout: B[k=j][col=dv] contiguous in j) ----
    const size_t vbase = ((size_t)bh * 64 + m) * 2048 + j0 + g * 8;
#pragma unroll
    for (int ks = 0; ks < 2; ++ks) {
      f16x8 pa = *(const f16x8*)(&P_lds[w][m][ks * 32 + g * 8]);
#pragma unroll
      for (int cf = 0; cf < 4; ++cf) {
        f16x8 vf = *(const f16x8*)(vtb + vbase + (size_t)cf * 32768 + ks * 32);
        acc_o[cf] = MFMA16(pa, vf, acc_o[cf]);
      }
    }
  }
  // ---- epilogue: normalize, write attn output [b][n][h*64+dv] fp16 ----
#pragma unroll
  for (int cf = 0; cf < 4; ++cf)
#pragma unroll
    for (int r = 0; r < 4; ++r) {
      const int i = i0 + w * 16 + g * 4 + r;
      const float o = acc_o[cf][r] / l_run[r];
      attnb[((size_t)(b * 2048 + i)) * 512 + h * 64 + cf * 16 + m] = (_Float16)o;
    }
}

extern "C" void kernel_launch(void* const* d_in, const int* in_sizes, int n_in,
                              void* d_out, int out_size, void* d_ws, size_t ws_size,
                              hipStream_t stream) {
  (void)in_sizes; (void)n_in; (void)out_size; (void)ws_size;
  const float* x    = (const float*)d_in[0];
  const float* Wq   = (const float*)d_in[1];
  const float* Wk   = (const float*)d_in[2];
  const float* Wv   = (const float*)d_in[3];
  const float* Wrel = (const float*)d_in[4];
  const float* bc   = (const float*)d_in[5];  // rel_content_bias [8*64]
  const float* bp   = (const float*)d_in[6];  // rel_pos_bias [8*64]
  const float* Wo   = (const float*)d_in[7];
  const float* bo   = (const float*)d_in[8];
  float* out = (float*)d_out;

  char* ws = (char*)d_ws;
  size_t off = 0;
  auto alloc = [&](size_t bytes) -> void* {
    void* p = ws + off;
    off += (bytes + 255) & ~(size_t)255;
    return p;
  };
  _Float16* xb    = (_Float16*)alloc(4096ull * 768 * 2);   // x in fp16
  _Float16* wqt   = (_Float16*)alloc(512ull * 768 * 2);    // Wq^T fp16
  _Float16* wkt   = (_Float16*)alloc(512ull * 768 * 2);
  _Float16* wvt   = (_Float16*)alloc(512ull * 768 * 2);
  _Float16* wrelt = (_Float16*)alloc(512ull * 192 * 2);
  _Float16* wot   = (_Float16*)alloc(768ull * 512 * 2);
  _Float16* posb  = (_Float16*)alloc(4096ull * 192 * 2);   // positional features (row 4095 = 0)
  _Float16* qcb   = (_Float16*)alloc(16ull * 2048 * 64 * 2);  // (q*scale + bc)  [b][h][n][64]
  _Float16* qpb   = (_Float16*)alloc(16ull * 2048 * 64 * 2);  // (q*scale + bp)
  _Float16* kbb   = (_Float16*)alloc(16ull * 2048 * 64 * 2);  // k [b][h][n][64]
  _Float16* vtb   = (_Float16*)alloc(16ull * 64 * 2048 * 2);  // v^T [b][h][64][n]
  _Float16* relkb = (_Float16*)alloc(8ull * 4096 * 64 * 2);   // rel_k [h][4096][64]
  _Float16* attnb = (_Float16*)alloc(4096ull * 512 * 2);      // attention output fp16

  cvt4_kernel<<<3072, 256, 0, stream>>>(x, xb, 786432);
  cvt_t_kernel<<<1536, 256, 0, stream>>>(Wq, wqt, 768, 512);
  cvt_t_kernel<<<1536, 256, 0, stream>>>(Wk, wkt, 768, 512);
  cvt_t_kernel<<<1536, 256, 0, stream>>>(Wv, wvt, 768, 512);
  cvt_t_kernel<<<384, 256, 0, stream>>>(Wrel, wrelt, 192, 512);
  cvt_t_kernel<<<1536, 256, 0, stream>>>(Wo, wot, 512, 768);
  pos_embed_kernel<<<4096, 128, 0, stream>>>(posb);

  dim3 gp(8, 64);  // (N/64, M/64)
  gemm_bt<0><<<gp, 256, 0, stream>>>(xb, wqt, 512, 768, qcb, qpb, bc, bp, nullptr);
  gemm_bt<1><<<gp, 256, 0, stream>>>(xb, wkt, 512, 768, kbb, nullptr, nullptr, nullptr, nullptr);
  gemm_bt<2><<<gp, 256, 0, stream>>>(xb, wvt, 512, 768, vtb, nullptr, nullptr, nullptr, nullptr);
  gemm_bt<3><<<gp, 256, 0, stream>>>(posb, wrelt, 512, 192, relkb, nullptr, nullptr, nullptr, nullptr);

  attn_kernel<<<dim3(32, 16), 256, 0, stream>>>(qcb, qpb, kbb, vtb, relkb, attnb);

  gemm_bt<4><<<dim3(12, 64), 256, 0, stream>>>(attnb, wot, 768, 512, nullptr, nullptr, bo, nullptr, out);
}

// Round 3
// 432.514 us; speedup vs baseline: 1.2240x; 1.2240x over previous
//
#include <hip/hip_runtime.h>
#include <hip/hip_bf16.h>
#include <math.h>

// Sizes (fixed): BATCH=2, SEQ=2048, DIM=768, HEADS=8, DK=DV=64, F=192, d_inner=512
// All internal compute in fp16 storage + fp32 MFMA accumulation.

typedef _Float16 f16x8 __attribute__((ext_vector_type(8)));
typedef _Float16 f16x4 __attribute__((ext_vector_type(4)));
typedef float f32x4 __attribute__((ext_vector_type(4)));

#define MFMA16(a, b, c) __builtin_amdgcn_mfma_f32_16x16x32_f16((a), (b), (c), 0, 0, 0)

// ---------------- f32 -> fp16 elementwise (vectorized x4) ----------------
__global__ __launch_bounds__(256) void cvt4_kernel(const float* __restrict__ in,
                                                   _Float16* __restrict__ out, int n4) {
  int idx = blockIdx.x * 256 + threadIdx.x;
  if (idx < n4) {
    float4 v = ((const float4*)in)[idx];
    f16x4 o;
    o[0] = (_Float16)v.x; o[1] = (_Float16)v.y; o[2] = (_Float16)v.z; o[3] = (_Float16)v.w;
    ((f16x4*)out)[idx] = o;
  }
}

// ---------------- f32 [K][N] -> fp16 transposed [N][K] ----------------
__global__ __launch_bounds__(256) void cvt_t_kernel(const float* __restrict__ in,
                                                    _Float16* __restrict__ out, int K, int N) {
  int idx = blockIdx.x * 256 + threadIdx.x;
  if (idx < K * N) {
    int k = idx / N, c = idx % N;
    out[(size_t)c * K + k] = (_Float16)in[idx];
  }
}

// ---- three [768][512] f32 weights -> one fp16 transposed [1536][768] ----
__global__ __launch_bounds__(256) void cvt_t3_kernel(const float* __restrict__ Wq,
                                                     const float* __restrict__ Wk,
                                                     const float* __restrict__ Wv,
                                                     _Float16* __restrict__ out) {
  int idx = blockIdx.x * 256 + threadIdx.x;  // over 3*768*512
  const int per = 768 * 512;
  int sel = idx / per, rem = idx - sel * per;
  int k = rem / 512, c = rem % 512;
  const float* W = (sel == 0) ? Wq : (sel == 1) ? Wk : Wv;
  out[((size_t)sel * 512 + c) * 768 + k] = (_Float16)W[rem];
}

// ---------------- positional embedding: posb [4096][192] fp16 ----------------
// row r: distance = r - 2047. cols 0..31 exp basis, 32..63 center mask,
// 64..95 gamma pdf (row-max normalized), 96..191 = sign * cols 0..95.
// row 4095 = zeros (pad; produces relk row 4095 = 0, computed-but-unread).
__global__ __launch_bounds__(128) void pos_embed_kernel(_Float16* __restrict__ posb) {
  __shared__ float sg[32];
  const int r = blockIdx.x, t = threadIdx.x;
  if (r >= 4095) {
    if (t < 96) {
      posb[(size_t)r * 192 + t] = (_Float16)0.f;
      posb[(size_t)r * 192 + 96 + t] = (_Float16)0.f;
    }
    return;
  }
  const float dist = (float)(r - 2047);
  const float absd = fabsf(dist);
  const float sgn = (dist > 0.f) ? 1.f : ((dist < 0.f) ? -1.f : 0.f);
  float val = 0.f;
  if (t < 32) {
    float e = 3.f + (float)t * (8.f / 31.f);
    float hl = exp2f(e);
    val = exp2f(-absd / hl);
  } else if (t < 64) {
    int i = t - 32;
    float cw = exp2f((float)(i + 1)) - 1.f;
    val = (cw > absd) ? 1.f : 0.f;
  } else if (t < 96) {
    int i = t - 64;
    float mean = 64.f * (float)(i + 1);
    float sd = 32.f;
    float conc = (mean / sd) * (mean / sd);
    float rate = mean / (sd * sd);
    float lu = (conc - 1.f) * logf(absd) - rate * absd;
    float ln_ = lgammaf(conc) - conc * logf(rate);
    val = expf(lu - ln_) + 1e-8f;
    sg[i] = val;
  }
  __syncthreads();
  if (t >= 64 && t < 96) {
    float mx = sg[0];
#pragma unroll
    for (int i = 1; i < 32; ++i) mx = fmaxf(mx, sg[i]);
    val = val / mx;
  }
  if (t < 96) {
    posb[(size_t)r * 192 + t] = (_Float16)val;
    posb[(size_t)r * 192 + 96 + t] = (_Float16)(sgn * val);
  }
}

// ---------------- fused QKV projection: [4096][768] x [1536][768]^T ----------------
// grid (24, 64), 256 thr = 4 waves; tile 64x64; col 0..511 -> q, 512..1023 -> k, 1024..1535 -> v.
__global__ __launch_bounds__(256) void gemm_qkv(
    const _Float16* __restrict__ A, const _Float16* __restrict__ Bt,
    _Float16* __restrict__ qc, _Float16* __restrict__ qp,
    _Float16* __restrict__ kb, _Float16* __restrict__ vt,
    const float* __restrict__ bc, const float* __restrict__ bp) {
  const int tid = threadIdx.x;
  const int w = tid >> 6, lane = tid & 63, g = lane >> 4, m = lane & 15;
  const int row0 = blockIdx.y * 64 + w * 16;
  const int c0 = blockIdx.x * 64;
  f32x4 acc[4] = {};
  const _Float16* Ap = A + (size_t)(row0 + m) * 768 + g * 8;
  const _Float16* Bp = Bt + (size_t)(c0 + m) * 768 + g * 8;
  for (int k0 = 0; k0 < 768; k0 += 32) {
    f16x8 a = *(const f16x8*)(Ap + k0);
#pragma unroll
    for (int cf = 0; cf < 4; ++cf) {
      f16x8 bfr = *(const f16x8*)(Bp + (size_t)cf * 16 * 768 + k0);
      acc[cf] = MFMA16(a, bfr, acc[cf]);
    }
  }
  const int proj = c0 >> 9;  // uniform per block
#pragma unroll
  for (int cf = 0; cf < 4; ++cf) {
    const int col = c0 + cf * 16 + m;
    const int c = col & 511, hh = c >> 6, dk = c & 63;
    float b0 = 0.f, b1 = 0.f;
    if (proj == 0) { b0 = bc[c]; b1 = bp[c]; }
#pragma unroll
    for (int r = 0; r < 4; ++r) {
      const int row = row0 + g * 4 + r;
      const int bb = row >> 11, n = row & 2047;
      const float v = acc[cf][r];
      if (proj == 0) {
        const size_t ad = ((size_t)(bb * 8 + hh) * 2048 + n) * 64 + dk;
        const float vs = v * 0.125f;  // DIM_KEY^-0.5
        qc[ad] = (_Float16)(vs + b0);
        qp[ad] = (_Float16)(vs + b1);
      } else if (proj == 1) {
        kb[((size_t)(bb * 8 + hh) * 2048 + n) * 64 + dk] = (_Float16)v;
      } else {
        vt[((size_t)(bb * 8 + hh) * 64 + dk) * 2048 + n] = (_Float16)v;
      }
    }
  }
}

// ---------------- generic MFMA GEMM: C[M][*] = A[M][K] * Bt[N][K]^T ----------------
// MODE 3: relk -> fp16 [h][4096][64]; MODE 4: out-proj -> f32 [row][N] + bias0[col]
template <int MODE>
__global__ __launch_bounds__(256) void gemm_bt(
    const _Float16* __restrict__ A, const _Float16* __restrict__ Bt, int N, int K,
    _Float16* __restrict__ out0, const float* __restrict__ bias0,
    float* __restrict__ outf) {
  const int tid = threadIdx.x;
  const int w = tid >> 6, lane = tid & 63, g = lane >> 4, m = lane & 15;
  const int row0 = blockIdx.y * 64 + w * 16;
  const int c0 = blockIdx.x * 64;
  f32x4 acc[4] = {};
  const _Float16* Ap = A + (size_t)(row0 + m) * K + g * 8;
  const _Float16* Bp = Bt + (size_t)(c0 + m) * K + g * 8;
  for (int k0 = 0; k0 < K; k0 += 32) {
    f16x8 a = *(const f16x8*)(Ap + k0);
#pragma unroll
    for (int cf = 0; cf < 4; ++cf) {
      f16x8 bfr = *(const f16x8*)(Bp + (size_t)cf * 16 * K + k0);
      acc[cf] = MFMA16(a, bfr, acc[cf]);
    }
  }
#pragma unroll
  for (int cf = 0; cf < 4; ++cf) {
    const int col = c0 + cf * 16 + m;
    const int hh = col >> 6, dk = col & 63;
#pragma unroll
    for (int r = 0; r < 4; ++r) {
      const int row = row0 + g * 4 + r;
      const float v = acc[cf][r];
      if (MODE == 3) {
        out0[((size_t)hh * 4096 + row) * 64 + dk] = (_Float16)v;
      } else {
        outf[(size_t)row * N + col] = v + bias0[col];
      }
    }
  }
}

// ---------------- fused rel-pos attention (1 wave / block, barrier-free) ----------------
// grid (128 i-tiles of 16 rows, 16 b*h), 64 threads.
// Per 64-wide j tile:
//   S_c = qc . K^T (8 MFMA)
//   R = qp . relk[d0'..d0'+80)^T (10 MFMA), d0' = j0 - i0 + 2032
//   shift gather fully in-register: Rs[lr][jj] = R[lr][16*cf + 15 + jj%16... ] via
//     u = 15 + m - lr in [0,30]; src fragment cf or cf+1, src lane (g, u&15)
//   online softmax; P -> fp16 -> wave-private LDS -> A-frags; acc += P.V (8 MFMA)
__global__ __launch_bounds__(64) void attn_kernel(
    const _Float16* __restrict__ qc, const _Float16* __restrict__ qp,
    const _Float16* __restrict__ kb, const _Float16* __restrict__ vtb,
    const _Float16* __restrict__ relkb, _Float16* __restrict__ attnb) {
  __shared__ __align__(16) _Float16 P_lds[16][72];  // rows 144B (16B-aligned)
  const int lane = threadIdx.x;
  const int g = lane >> 4, m = lane & 15;
  const int i0 = blockIdx.x * 16;
  const int bh = blockIdx.y;
  const int h = bh & 7, b = bh >> 3;

  const size_t qbase = ((size_t)bh * 2048 + i0 + m) * 64 + g * 8;
  f16x8 qcf0 = *(const f16x8*)(qc + qbase);
  f16x8 qcf1 = *(const f16x8*)(qc + qbase + 32);
  f16x8 qpf0 = *(const f16x8*)(qp + qbase);
  f16x8 qpf1 = *(const f16x8*)(qp + qbase + 32);

  f32x4 acc_o[4] = {};
  float m_run[4], l_run[4];
#pragma unroll
  for (int r = 0; r < 4; ++r) { m_run[r] = -1e30f; l_run[r] = 0.f; }

  for (int jt = 0; jt < 32; ++jt) {
    const int j0 = jt * 64;
    // ---- content logits S_c [16 x 64] ----
    f32x4 sc[4] = {};
    const size_t kbase = ((size_t)bh * 2048 + j0 + m) * 64 + g * 8;
#pragma unroll
    for (int cf = 0; cf < 4; ++cf) {
      f16x8 b0 = *(const f16x8*)(kb + kbase + (size_t)cf * 1024);
      f16x8 b1 = *(const f16x8*)(kb + kbase + (size_t)cf * 1024 + 32);
      sc[cf] = MFMA16(qcf0, b0, sc[cf]);
      sc[cf] = MFMA16(qcf1, b1, sc[cf]);
    }
    // ---- rel logits band R [16 x 80] ----
    // band col c' maps to relk row d0p + c'; gather target t' = 15 + jj - lr + 16*cf
    const int d0p = j0 - i0 + 2032;  // in [0, 4016]; rows d0p+c' in [0, 4095]
    const size_t rbase = ((size_t)h * 4096 + d0p + m) * 64 + g * 8;
    f32x4 rc[5] = {};
#pragma unroll
    for (int cf = 0; cf < 5; ++cf) {
      f16x8 b0 = *(const f16x8*)(relkb + rbase + (size_t)cf * 1024);
      f16x8 b1 = *(const f16x8*)(relkb + rbase + (size_t)cf * 1024 + 32);
      rc[cf] = MFMA16(qpf0, b0, rc[cf]);
      rc[cf] = MFMA16(qpf1, b1, rc[cf]);
    }
    // ---- in-register shift gather + add ----
#pragma unroll
    for (int r = 0; r < 4; ++r) {
      const int lr = g * 4 + r;
      const int u = 15 + m - lr;          // in [0, 30]
      const int src = (g << 4) | (u & 15);
      const bool hi = (m > lr);           // u >= 16
      float sh0 = __shfl(rc[0][r], src);
      float sh1 = __shfl(rc[1][r], src);
      float sh2 = __shfl(rc[2][r], src);
      float sh3 = __shfl(rc[3][r], src);
      float sh4 = __shfl(rc[4][r], src);
      sc[0][r] += hi ? sh1 : sh0;
      sc[1][r] += hi ? sh2 : sh1;
      sc[2][r] += hi ? sh3 : sh2;
      sc[3][r] += hi ? sh4 : sh3;
    }
    // ---- online softmax (rows owned per lane: r=0..3) ----
    float P[4][4];
#pragma unroll
    for (int r = 0; r < 4; ++r) {
      float mx = fmaxf(fmaxf(sc[0][r], sc[1][r]), fmaxf(sc[2][r], sc[3][r]));
      mx = fmaxf(mx, __shfl_xor(mx, 1));
      mx = fmaxf(mx, __shfl_xor(mx, 2));
      mx = fmaxf(mx, __shfl_xor(mx, 4));
      mx = fmaxf(mx, __shfl_xor(mx, 8));
      const float mnew = fmaxf(m_run[r], mx);
      const float corr = __expf(m_run[r] - mnew);
      float rs = 0.f;
#pragma unroll
      for (int cf = 0; cf < 4; ++cf) {
        float p = __expf(sc[cf][r] - mnew);
        P[cf][r] = p;
        rs += p;
      }
      rs += __shfl_xor(rs, 1);
      rs += __shfl_xor(rs, 2);
      rs += __shfl_xor(rs, 4);
      rs += __shfl_xor(rs, 8);
      l_run[r] = l_run[r] * corr + rs;
      m_run[r] = mnew;
#pragma unroll
      for (int cf = 0; cf < 4; ++cf) acc_o[cf][r] *= corr;
    }
    // ---- P -> fp16 -> wave-private LDS (no barrier; same-wave DS ops are ordered) ----
#pragma unroll
    for (int cf = 0; cf < 4; ++cf)
#pragma unroll
      for (int r = 0; r < 4; ++r)
        P_lds[g * 4 + r][cf * 16 + m] = (_Float16)P[cf][r];
    // ---- PV: acc_o += P . V ----
    const size_t vbase = ((size_t)bh * 64 + m) * 2048 + j0 + g * 8;
#pragma unroll
    for (int ks = 0; ks < 2; ++ks) {
      f16x8 pa = *(const f16x8*)(&P_lds[m][ks * 32 + g * 8]);
#pragma unroll
      for (int cf = 0; cf < 4; ++cf) {
        f16x8 vf = *(const f16x8*)(vtb + vbase + (size_t)cf * 32768 + ks * 32);
        acc_o[cf] = MFMA16(pa, vf, acc_o[cf]);
      }
    }
  }
  // ---- epilogue: normalize, write attn output [b][n][h*64+dv] fp16 ----
#pragma unroll
  for (int cf = 0; cf < 4; ++cf)
#pragma unroll
    for (int r = 0; r < 4; ++r) {
      const int i = i0 + g * 4 + r;
      const float o = acc_o[cf][r] / l_run[r];
      attnb[((size_t)(b * 2048 + i)) * 512 + h * 64 + cf * 16 + m] = (_Float16)o;
    }
}

extern "C" void kernel_launch(void* const* d_in, const int* in_sizes, int n_in,
                              void* d_out, int out_size, void* d_ws, size_t ws_size,
                              hipStream_t stream) {
  (void)in_sizes; (void)n_in; (void)out_size; (void)ws_size;
  const float* x    = (const float*)d_in[0];
  const float* Wq   = (const float*)d_in[1];
  const float* Wk   = (const float*)d_in[2];
  const float* Wv   = (const float*)d_in[3];
  const float* Wrel = (const float*)d_in[4];
  const float* bc   = (const float*)d_in[5];  // rel_content_bias [8*64]
  const float* bp   = (const float*)d_in[6];  // rel_pos_bias [8*64]
  const float* Wo   = (const float*)d_in[7];
  const float* bo   = (const float*)d_in[8];
  float* out = (float*)d_out;

  char* ws = (char*)d_ws;
  size_t off = 0;
  auto alloc = [&](size_t bytes) -> void* {
    void* p = ws + off;
    off += (bytes + 255) & ~(size_t)255;
    return p;
  };
  _Float16* xb     = (_Float16*)alloc(4096ull * 768 * 2);    // x in fp16
  _Float16* wqkvt  = (_Float16*)alloc(1536ull * 768 * 2);    // [Wq;Wk;Wv]^T fp16
  _Float16* wrelt  = (_Float16*)alloc(512ull * 192 * 2);
  _Float16* wot    = (_Float16*)alloc(768ull * 512 * 2);
  _Float16* posb   = (_Float16*)alloc(4096ull * 192 * 2);    // positional features (row 4095 = 0)
  _Float16* qcb    = (_Float16*)alloc(16ull * 2048 * 64 * 2);   // (q*scale + bc)  [b][h][n][64]
  _Float16* qpb    = (_Float16*)alloc(16ull * 2048 * 64 * 2);   // (q*scale + bp)
  _Float16* kbb    = (_Float16*)alloc(16ull * 2048 * 64 * 2);   // k [b][h][n][64]
  _Float16* vtb    = (_Float16*)alloc(16ull * 64 * 2048 * 2);   // v^T [b][h][64][n]
  _Float16* relkb  = (_Float16*)alloc(8ull * 4096 * 64 * 2);    // rel_k [h][4096][64]
  _Float16* attnb  = (_Float16*)alloc(4096ull * 512 * 2);       // attention output fp16

  cvt4_kernel<<<3072, 256, 0, stream>>>(x, xb, 786432);
  cvt_t3_kernel<<<4608, 256, 0, stream>>>(Wq, Wk, Wv, wqkvt);
  cvt_t_kernel<<<384, 256, 0, stream>>>(Wrel, wrelt, 192, 512);
  cvt_t_kernel<<<1536, 256, 0, stream>>>(Wo, wot, 512, 768);
  pos_embed_kernel<<<4096, 128, 0, stream>>>(posb);

  gemm_qkv<<<dim3(24, 64), 256, 0, stream>>>(xb, wqkvt, qcb, qpb, kbb, vtb, bc, bp);
  gemm_bt<3><<<dim3(8, 64), 256, 0, stream>>>(posb, wrelt, 512, 192, relkb, nullptr, nullptr);

  attn_kernel<<<dim3(128, 16), 64, 0, stream>>>(qcb, qpb, kbb, vtb, relkb, attnb);

  gemm_bt<4><<<dim3(12, 64), 256, 0, stream>>>(attnb, wot, 768, 512, nullptr, bo, out);
}